// Round 7
// baseline (390.756 us; speedup 1.0000x reference)
//
#include <hip/hip_runtime.h>

#define BB 4
#define CC 96
#define NN 3136
#define FLTMAX 3.402823466e+38f

typedef unsigned short ushort_t;
typedef __attribute__((ext_vector_type(8))) short bf16x8;
typedef __attribute__((ext_vector_type(4))) float f32x4;

// fp32 -> bf16 round-to-nearest-even
__device__ __forceinline__ ushort_t f2bf(float f) {
    unsigned u = __float_as_uint(f);
    unsigned r = (u + 0x7fff + ((u >> 16) & 1)) >> 16;
    return (ushort_t)r;
}
__device__ __forceinline__ float bf2f(ushort_t us) {
    return __uint_as_float(((unsigned)us) << 16);
}

// htile layout (per batch):
//   idx(n,c) = (((n>>5)*12 + (c>>3))*32 + (n&31))*8 + (c&7)

// ---------------- K1: fc1 -> h (b,c,n) + x2 + bf16-split htile + hT ----------
__global__ __launch_bounds__(256) void k_fc1(const float* __restrict__ x, const float* __restrict__ w,
                                             const float* __restrict__ bias, float* __restrict__ h,
                                             float* __restrict__ x2g,
                                             ushort_t* __restrict__ hAhi, ushort_t* __restrict__ hAlo,
                                             float* __restrict__ hT) {
    __shared__ float sm[96 * 98 + 96 * 64];
    float* wT = sm;              // [c][o] pad 98
    float* xl = sm + 96 * 98;    // [c][64]
    const int tid = threadIdx.x;
    const int n0 = blockIdx.x * 64;
    const int b = blockIdx.y;
    for (int i = tid; i < 96 * 96; i += 256) {
        int o = i / 96, c = i - o * 96;
        wT[c * 98 + o] = w[i];
    }
    const float* xb = x + (size_t)b * CC * NN;
    for (int i = tid; i < 96 * 64; i += 256) {
        int c = i >> 6, nl = i & 63;
        xl[i] = xb[(size_t)c * NN + n0 + nl];
    }
    __syncthreads();
    const int tr = tid >> 4, tc = tid & 15;
    float acc[6][4];
#pragma unroll
    for (int i = 0; i < 6; ++i)
#pragma unroll
        for (int j = 0; j < 4; ++j) acc[i][j] = 0.f;
#pragma unroll 4
    for (int c = 0; c < 96; ++c) {
        float4 xv = *(const float4*)&xl[c * 64 + tc * 4];
        const float* wp = &wT[c * 98 + tr * 6];
        float2 w01 = *(const float2*)(wp);
        float2 w23 = *(const float2*)(wp + 2);
        float2 w45 = *(const float2*)(wp + 4);
        float wv[6] = {w01.x, w01.y, w23.x, w23.y, w45.x, w45.y};
        float xj[4] = {xv.x, xv.y, xv.z, xv.w};
#pragma unroll
        for (int i = 0; i < 6; ++i)
#pragma unroll
            for (int j = 0; j < 4; ++j) acc[i][j] = fmaf(wv[i], xj[j], acc[i][j]);
    }
    float* hb = h + (size_t)b * CC * NN;
    float* hTb = hT + (size_t)b * NN * 96;
    ushort_t* thi = hAhi + (size_t)b * 602112;
    ushort_t* tlo = hAlo + (size_t)b * 602112;
#pragma unroll
    for (int i = 0; i < 6; ++i) {
        float bi = bias[tr * 6 + i];
        acc[i][0] += bi; acc[i][1] += bi; acc[i][2] += bi; acc[i][3] += bi;
        float4 o4 = make_float4(acc[i][0], acc[i][1], acc[i][2], acc[i][3]);
        *(float4*)&hb[(size_t)(tr * 6 + i) * NN + n0 + tc * 4] = o4;
        const int c = tr * 6 + i;
        const int cpart = c >> 3;   // 12 parts of 8 channels
#pragma unroll
        for (int j = 0; j < 4; ++j) {
            const int n = n0 + tc * 4 + j;
            const int idx = (((n >> 5) * 12 + cpart) * 32 + (n & 31)) * 8 + (c & 7);
            ushort_t hi = f2bf(acc[i][j]);
            float lo = acc[i][j] - bf2f(hi);
            thi[idx] = hi;
            tlo[idx] = f2bf(lo);
            hTb[(size_t)n * 96 + c] = acc[i][j];
        }
    }
    __syncthreads();   // wT/xl reads done -> reuse sm[0..1024) for x2 partials
#pragma unroll
    for (int j = 0; j < 4; ++j) {
        float s = 0.f;
#pragma unroll
        for (int i = 0; i < 6; ++i) s = fmaf(acc[i][j], acc[i][j], s);
        sm[tr * 64 + tc * 4 + j] = s;
    }
    __syncthreads();
    if (tid < 64) {
        float s = 0.f;
#pragma unroll
        for (int t = 0; t < 16; ++t) s += sm[t * 64 + tid];
        x2g[(size_t)b * NN + n0 + tid] = s;
    }
}

// ---------------- K3: MFMA distance + per-lane exact top-9 -------------------
// grid (98 n-blocks of 32, B), 128 thr = 2 waves; wave w owns n = nb*32+w*16+ln.
// Each lane (ln,lq) keeps exact top-9 of its lq m-stream (784 values) in sorted
// registers; union of 4 lq lists = 36 candidates per n (guaranteed superset of
// approx-score top-9). No LDS, no splits, no barriers.
__global__ __launch_bounds__(128) void k_dist(const ushort_t* __restrict__ hAhi,
                                              const ushort_t* __restrict__ hAlo,
                                              const float* __restrict__ x2,
                                              int* __restrict__ cand_idx) {
    const int tid = threadIdx.x;
    const int nb = blockIdx.x, b = blockIdx.y;
    const int w = tid >> 6, l = tid & 63;
    const int ln = l & 15, lq = l >> 4;
    const int kl_off = lq * 256;
    const ushort_t* hHi = hAhi + (size_t)b * 602112;
    const ushort_t* hLo = hAlo + (size_t)b * 602112;
    const float* x2b = x2 + (size_t)b * NN;

    // preload B-frags (n-side) for 3 k-steps, hi & lo
    const int lane32n = w * 16 + ln;
    bf16x8 bhi[3], blo[3];
#pragma unroll
    for (int ks = 0; ks < 3; ++ks) {
        const int off = nb * 3072 + ks * 1024 + kl_off + lane32n * 8;
        bhi[ks] = *(const bf16x8*)(hHi + off);
        blo[ks] = *(const bf16x8*)(hLo + off);
    }
    const int aoff0 = kl_off + ln * 8;          // msub even (lane32 = ln)
    const int aoff1 = kl_off + (16 + ln) * 8;   // msub odd  (lane32 = 16+ln)

    // sorted-descending top-9 (lv[0] = worst kept = 9th best)
    float lv[9]; int li[9];
#pragma unroll
    for (int k = 0; k < 9; ++k) { lv[k] = FLTMAX; li[k] = 0x7fffffff; }

    for (int t = 0; t < 49; ++t) {
        const int m0 = t * 64;
        f32x4 acc0 = {0.f, 0.f, 0.f, 0.f};
        f32x4 acc1 = {0.f, 0.f, 0.f, 0.f};
        f32x4 acc2 = {0.f, 0.f, 0.f, 0.f};
        f32x4 acc3 = {0.f, 0.f, 0.f, 0.f};
        const int abase = t * 6144;
#pragma unroll
        for (int ks = 0; ks < 3; ++ks) {
            const int base = abase + ks * 1024;
            // A-hi fragments used twice (x bhi and x blo)
            bf16x8 a0 = *(const bf16x8*)(hHi + base + aoff0);
            bf16x8 a1 = *(const bf16x8*)(hHi + base + aoff1);
            bf16x8 a2 = *(const bf16x8*)(hHi + base + 3072 + aoff0);
            bf16x8 a3 = *(const bf16x8*)(hHi + base + 3072 + aoff1);
            acc0 = __builtin_amdgcn_mfma_f32_16x16x32_bf16(a0, bhi[ks], acc0, 0, 0, 0);
            acc1 = __builtin_amdgcn_mfma_f32_16x16x32_bf16(a1, bhi[ks], acc1, 0, 0, 0);
            acc2 = __builtin_amdgcn_mfma_f32_16x16x32_bf16(a2, bhi[ks], acc2, 0, 0, 0);
            acc3 = __builtin_amdgcn_mfma_f32_16x16x32_bf16(a3, bhi[ks], acc3, 0, 0, 0);
            acc0 = __builtin_amdgcn_mfma_f32_16x16x32_bf16(a0, blo[ks], acc0, 0, 0, 0);
            acc1 = __builtin_amdgcn_mfma_f32_16x16x32_bf16(a1, blo[ks], acc1, 0, 0, 0);
            acc2 = __builtin_amdgcn_mfma_f32_16x16x32_bf16(a2, blo[ks], acc2, 0, 0, 0);
            acc3 = __builtin_amdgcn_mfma_f32_16x16x32_bf16(a3, blo[ks], acc3, 0, 0, 0);
            bf16x8 c0 = *(const bf16x8*)(hLo + base + aoff0);
            bf16x8 c1 = *(const bf16x8*)(hLo + base + aoff1);
            bf16x8 c2 = *(const bf16x8*)(hLo + base + 3072 + aoff0);
            bf16x8 c3 = *(const bf16x8*)(hLo + base + 3072 + aoff1);
            acc0 = __builtin_amdgcn_mfma_f32_16x16x32_bf16(c0, bhi[ks], acc0, 0, 0, 0);
            acc1 = __builtin_amdgcn_mfma_f32_16x16x32_bf16(c1, bhi[ks], acc1, 0, 0, 0);
            acc2 = __builtin_amdgcn_mfma_f32_16x16x32_bf16(c2, bhi[ks], acc2, 0, 0, 0);
            acc3 = __builtin_amdgcn_mfma_f32_16x16x32_bf16(c3, bhi[ks], acc3, 0, 0, 0);
        }
        // scan: lane owns n = nb*32 + lane32n; rows m = m0 + msub*16 + lq*4 + r
#pragma unroll
        for (int msub = 0; msub < 4; ++msub) {
            f32x4 a = (msub == 0) ? acc0 : (msub == 1) ? acc1 : (msub == 2) ? acc2 : acc3;
            const int mb = m0 + msub * 16 + lq * 4;
            float4 xv = *(const float4*)&x2b[mb];
            float s0 = fmaf(-2.f, a[0], xv.x);
            float s1 = fmaf(-2.f, a[1], xv.y);
            float s2 = fmaf(-2.f, a[2], xv.z);
            float s3 = fmaf(-2.f, a[3], xv.w);
            unsigned msk = (s0 < lv[0] ? 1u : 0u) | (s1 < lv[0] ? 2u : 0u) |
                           (s2 < lv[0] ? 4u : 0u) | (s3 < lv[0] ? 8u : 0u);
            while (msk) {
                const int r = __builtin_ctz(msk);
                msk &= msk - 1;
                float v01 = (r & 1) ? s1 : s0;
                float v23 = (r & 1) ? s3 : s2;
                float v = (r & 2) ? v23 : v01;
                const int m = mb + r;
                // guarded branchless sorted insert (drop old head = old 9th-best)
                const bool p_ = v < lv[0];
                float cv = p_ ? v : lv[0];
                int ci = p_ ? m : li[0];
#pragma unroll
                for (int k = 1; k < 9; ++k) {
                    float ok = lv[k]; int oi = li[k];
                    const bool sw = ok > cv;
                    lv[k - 1] = sw ? ok : cv;
                    li[k - 1] = sw ? oi : ci;
                    cv = sw ? cv : ok;
                    ci = sw ? ci : oi;
                }
                lv[8] = cv; li[8] = ci;
            }
        }
    }
    // write 9 candidate indices per (n, lq)
    const int n = nb * 32 + lane32n;
    int* dst = cand_idx + ((size_t)b * NN + n) * 36 + lq * 9;
#pragma unroll
    for (int k = 0; k < 9; ++k) dst[k] = li[k];
}

// ---------------- K4: exact fp32 rescore of 36 candidates -> idx9 ------------
// grid 196 blocks x 256 thr: 4 threads per row n, 64 rows per block.
__global__ __launch_bounds__(256) void k_merge(const int* __restrict__ cand_idx,
                                               const float* __restrict__ hT,
                                               const float* __restrict__ x2,
                                               int* __restrict__ idx9) {
    __shared__ float mv[64 * 36];
    __shared__ int   mi[64 * 36];
    const int tid = threadIdx.x;
    const int nl = tid >> 2, part = tid & 3;
    const int n = blockIdx.x * 64 + nl;     // global row id in [0, BB*NN)
    const int b = n / NN;
    const int nn = n - b * NN;
    const float* hTb = hT + (size_t)b * NN * 96;
    const float* x2b = x2 + (size_t)b * NN;
    float4 ro[24];
    {
        const float* own = hTb + (size_t)nn * 96;
#pragma unroll
        for (int i = 0; i < 24; ++i) ro[i] = *(const float4*)&own[i * 4];
    }
#pragma unroll
    for (int jj = 0; jj < 9; ++jj) {
        const int j = part * 9 + jj;
        const int cj = cand_idx[(size_t)n * 36 + j];
        const float* cr = hTb + (size_t)cj * 96;
        float dot = 0.f;
#pragma unroll
        for (int i = 0; i < 24; ++i) {
            float4 cv = *(const float4*)&cr[i * 4];
            dot = fmaf(ro[i].x, cv.x, dot);
            dot = fmaf(ro[i].y, cv.y, dot);
            dot = fmaf(ro[i].z, cv.z, dot);
            dot = fmaf(ro[i].w, cv.w, dot);
        }
        mv[nl * 36 + j] = fmaf(-2.f, dot, x2b[cj]);
        mi[nl * 36 + j] = cj;
    }
    __syncthreads();
    if (tid < 64) {
        const int base = tid * 36;
        const size_t grow = (size_t)(blockIdx.x * 64 + tid);
        for (int kk = 0; kk < 9; ++kk) {
            float bv = FLTMAX; int bi = 0x7fffffff; int bs = 0;
            for (int j = 0; j < 36; ++j) {
                float v = mv[base + j]; int ii = mi[base + j];
                if (v < bv || (v == bv && ii < bi)) { bv = v; bi = ii; bs = j; }
            }
            mv[base + bs] = FLTMAX;
            idx9[grow * 9 + kk] = bi;
        }
    }
}

// ---------------- K5: [U;V] @ h -> acT (b,n,384); weight transform fused -----
__global__ __launch_bounds__(256) void k_ac(const float* __restrict__ h, const float* __restrict__ gw,
                                            const float* __restrict__ gb, float* __restrict__ acT) {
    __shared__ float sm[96 * 98 + 96 * 64];
    float* wT = sm;
    float* hl = sm + 96 * 98;
    const int tid = threadIdx.x;
    const int n0 = blockIdx.x * 64, ot = blockIdx.y, b = blockIdx.z;
    // rows 0..191 of M = W1 - W2, rows 192..383 = W2  (W=[W1|W2], 192x192)
    for (int i = tid; i < 96 * 96; i += 256) {
        int o = i / 96, c = i - o * 96;
        float v;
        if (ot < 2) {
            const float* gwp = gw + (size_t)(ot * 96 + o) * 192;
            v = gwp[c] - gwp[96 + c];
        } else {
            v = gw[(size_t)((ot - 2) * 96 + o) * 192 + 96 + c];
        }
        wT[c * 98 + o] = v;
    }
    const float* hb = h + (size_t)b * CC * NN;
    for (int i = tid; i < 96 * 64; i += 256) {
        int c = i >> 6, nl = i & 63;
        hl[i] = hb[(size_t)c * NN + n0 + nl];
    }
    __syncthreads();
    const int tr = tid >> 4, tc = tid & 15;
    float acc[6][4];
#pragma unroll
    for (int i = 0; i < 6; ++i)
#pragma unroll
        for (int j = 0; j < 4; ++j) acc[i][j] = 0.f;
#pragma unroll 4
    for (int c = 0; c < 96; ++c) {
        float4 xv = *(const float4*)&hl[c * 64 + tc * 4];
        const float* wp = &wT[c * 98 + tr * 6];
        float2 w01 = *(const float2*)(wp);
        float2 w23 = *(const float2*)(wp + 2);
        float2 w45 = *(const float2*)(wp + 4);
        float wv[6] = {w01.x, w01.y, w23.x, w23.y, w45.x, w45.y};
        float xj[4] = {xv.x, xv.y, xv.z, xv.w};
#pragma unroll
        for (int i = 0; i < 6; ++i)
#pragma unroll
            for (int j = 0; j < 4; ++j) acc[i][j] = fmaf(wv[i], xj[j], acc[i][j]);
    }
    const int obase = ot * 96 + tr * 6;
    float bs[6];
#pragma unroll
    for (int i = 0; i < 6; ++i) bs[i] = (ot < 2) ? gb[obase + i] : 0.f;
#pragma unroll
    for (int j = 0; j < 4; ++j) {
        float* dst = acT + ((size_t)b * NN + n0 + tc * 4 + j) * 384 + obase;
        *(float2*)(dst + 0) = make_float2(acc[0][j] + bs[0], acc[1][j] + bs[1]);
        *(float2*)(dst + 2) = make_float2(acc[2][j] + bs[2], acc[3][j] + bs[3]);
        *(float2*)(dst + 4) = make_float2(acc[4][j] + bs[4], acc[5][j] + bs[5]);
    }
}

// ---------------- K6: gather neighbors, k-max, relu -> gT (b,n,192) ----------
__global__ __launch_bounds__(256) void k_gather(const float* __restrict__ acT, const int* __restrict__ idx9,
                                                float* __restrict__ gT) {
    const int lane = threadIdx.x & 63;
    const int wv = threadIdx.x >> 6;
    const int b = blockIdx.y;
    const int nb = blockIdx.x * 16 + wv * 4;
    for (int r = 0; r < 4; ++r) {
        const int n = nb + r;
        const float* ar = acT + ((size_t)b * NN + n) * 384;
        float a0 = ar[lane], a1 = ar[lane + 64], a2 = ar[lane + 128];
        const int* ip = idx9 + ((size_t)b * NN + n) * 9;
        int jj[9];
#pragma unroll
        for (int k = 0; k < 9; ++k) jj[k] = ip[k];
        float m0 = -FLTMAX, m1 = -FLTMAX, m2 = -FLTMAX;
#pragma unroll
        for (int k = 0; k < 9; ++k) {
            const float* cr = acT + ((size_t)b * NN + jj[k]) * 384 + 192;
            m0 = fmaxf(m0, a0 + cr[lane]);
            m1 = fmaxf(m1, a1 + cr[lane + 64]);
            m2 = fmaxf(m2, a2 + cr[lane + 128]);
        }
        float* gr = gT + ((size_t)b * NN + n) * 192;
        gr[lane] = fmaxf(m0, 0.f);
        gr[lane + 64] = fmaxf(m1, 0.f);
        gr[lane + 128] = fmaxf(m2, 0.f);
    }
}

// ---------------- K7: fc2 (NT gemm) -> out, fused channel mean/max -----------
__global__ __launch_bounds__(256) void k_fc2(const float* __restrict__ gT, const float* __restrict__ w,
                                             const float* __restrict__ bias, float* __restrict__ out,
                                             float* __restrict__ sa_in) {
    __shared__ float Wc[96 * 36];
    __shared__ float Gc[64 * 36];
    const int tid = threadIdx.x;
    const int n0 = blockIdx.x * 64, b = blockIdx.y;
    const int tr = tid >> 4, tc = tid & 15;
    float acc[6][4];
#pragma unroll
    for (int i = 0; i < 6; ++i)
#pragma unroll
        for (int j = 0; j < 4; ++j) acc[i][j] = 0.f;
    for (int kc = 0; kc < 192; kc += 32) {
        for (int i = tid; i < 96 * 32; i += 256) {
            int c = i >> 5, k = i & 31;
            Wc[c * 36 + k] = w[(size_t)c * 192 + kc + k];
        }
        for (int i = tid; i < 64 * 32; i += 256) {
            int nl = i >> 5, k = i & 31;
            Gc[nl * 36 + k] = gT[((size_t)b * NN + n0 + nl) * 192 + kc + k];
        }
        __syncthreads();
#pragma unroll
        for (int k = 0; k < 32; k += 4) {
            float4 wv[6]; float4 gv[4];
#pragma unroll
            for (int i = 0; i < 6; ++i) wv[i] = *(const float4*)&Wc[(tr * 6 + i) * 36 + k];
#pragma unroll
            for (int j = 0; j < 4; ++j) gv[j] = *(const float4*)&Gc[(tc * 4 + j) * 36 + k];
#pragma unroll
            for (int i = 0; i < 6; ++i)
#pragma unroll
                for (int j = 0; j < 4; ++j) {
                    acc[i][j] = fmaf(wv[i].x, gv[j].x, acc[i][j]);
                    acc[i][j] = fmaf(wv[i].y, gv[j].y, acc[i][j]);
                    acc[i][j] = fmaf(wv[i].z, gv[j].z, acc[i][j]);
                    acc[i][j] = fmaf(wv[i].w, gv[j].w, acc[i][j]);
                }
        }
        __syncthreads();
    }
    float* ob = out + (size_t)b * CC * NN;
    float bs[6];
#pragma unroll
    for (int i = 0; i < 6; ++i) bs[i] = bias[tr * 6 + i];
    float ps[4], pm[4];
#pragma unroll
    for (int j = 0; j < 4; ++j) { ps[j] = 0.f; pm[j] = -FLTMAX; }
#pragma unroll
    for (int i = 0; i < 6; ++i) {
        float o0 = acc[i][0] + bs[i], o1 = acc[i][1] + bs[i];
        float o2 = acc[i][2] + bs[i], o3 = acc[i][3] + bs[i];
        *(float4*)&ob[(size_t)(tr * 6 + i) * NN + n0 + tc * 4] = make_float4(o0, o1, o2, o3);
        ps[0] += o0; ps[1] += o1; ps[2] += o2; ps[3] += o3;
        pm[0] = fmaxf(pm[0], o0); pm[1] = fmaxf(pm[1], o1);
        pm[2] = fmaxf(pm[2], o2); pm[3] = fmaxf(pm[3], o3);
    }
    // channel mean/max reduction across tr (16 groups of 6 channels)
    float* red  = Wc;          // [16][64]
    float* red2 = Wc + 1024;   // [16][64]
#pragma unroll
    for (int j = 0; j < 4; ++j) {
        red[tr * 64 + tc * 4 + j]  = ps[j];
        red2[tr * 64 + tc * 4 + j] = pm[j];
    }
    __syncthreads();
    if (tid < 64) {
        float s_ = 0.f, m_ = -FLTMAX;
#pragma unroll
        for (int t = 0; t < 16; ++t) { s_ += red[t * 64 + tid]; m_ = fmaxf(m_, red2[t * 64 + tid]); }
        sa_in[(size_t)b * 2 * NN + n0 + tid] = s_ * (1.0f / 96.0f);
        sa_in[(size_t)b * 2 * NN + NN + n0 + tid] = m_;
    }
}

// ---------------- K9: 7x7 conv + sigmoid + out*att + shortcut (in place) -----
__global__ __launch_bounds__(256) void k_att(const float* __restrict__ sa_in, const float* __restrict__ sw,
                                             const float* __restrict__ x, float* __restrict__ out) {
    int n = blockIdx.x * 256 + threadIdx.x;
    int b = blockIdx.y;
    if (n >= NN) return;
    int y = n / 56, xw = n - y * 56;
    float acc = 0.f;
#pragma unroll
    for (int ci = 0; ci < 2; ++ci) {
        const float* sb = sa_in + ((size_t)b * 2 + ci) * NN;
#pragma unroll
        for (int dy = 0; dy < 7; ++dy) {
            int yy = y + dy - 3;
            if ((unsigned)yy < 56u) {
#pragma unroll
                for (int dx = 0; dx < 7; ++dx) {
                    int xx = xw + dx - 3;
                    if ((unsigned)xx < 56u)
                        acc = fmaf(sb[yy * 56 + xx], sw[(ci * 7 + dy) * 7 + dx], acc);
                }
            }
        }
    }
    float att = 1.f / (1.f + expf(-acc));
    const float* xb = x + (size_t)b * CC * NN + n;
    float* ob = out + (size_t)b * CC * NN + n;
#pragma unroll 4
    for (int c = 0; c < 96; ++c) {
        size_t o = (size_t)c * NN;
        ob[o] = fmaf(ob[o], att, xb[o]);
    }
}

extern "C" void kernel_launch(void* const* d_in, const int* in_sizes, int n_in,
                              void* d_out, int out_size, void* d_ws, size_t ws_size,
                              hipStream_t stream) {
    (void)in_sizes; (void)n_in; (void)out_size; (void)ws_size;
    const float* x       = (const float*)d_in[0];
    const float* fc1_w   = (const float*)d_in[1];
    const float* fc1_b   = (const float*)d_in[2];
    const float* gconv_w = (const float*)d_in[3];
    const float* gconv_b = (const float*)d_in[4];
    const float* fc2_w   = (const float*)d_in[5];
    const float* fc2_b   = (const float*)d_in[6];
    const float* sa_w    = (const float*)d_in[7];
    float* out = (float*)d_out;

    // workspace layout (floats)
    float* ws   = (float*)d_ws;
    float* h    = ws;                                   // 1,204,224
    float* x2   = h + (size_t)BB * CC * NN;             // 12,544
    int*   idx9 = (int*)(x2 + BB * NN);                 // 112,896 ints
    float* acT  = (float*)(idx9 + (size_t)BB * NN * 9); // 4,816,896
    float* gT   = acT + (size_t)BB * NN * 384;          // 2,408,448
    // overlays (disjoint lifetimes):
    // acT region: [hAhi | hAlo | hT] live k_fc1 -> k_merge; acT written by k_ac after
    ushort_t* hAhi = (ushort_t*)acT;                    // per batch 602112 ushorts
    ushort_t* hAlo = hAhi + (size_t)BB * 602112;
    float* hT = acT + (size_t)2408448;                  // 1,204,224 floats
    // cand_idx lives in gT region (written k_dist, read k_merge; gT written k_gather later)
    int* cand_idx = (int*)gT;                           // 12544*36 ints
    float* sa_in = gT + (size_t)BB * NN * 192;          // 25,088

    k_fc1   <<<dim3(49, BB), 256, 0, stream>>>(x, fc1_w, fc1_b, h, x2, hAhi, hAlo, hT);
    k_dist  <<<dim3(98, BB), 128, 0, stream>>>(hAhi, hAlo, x2, cand_idx);
    k_merge <<<dim3(196), 256, 0, stream>>>(cand_idx, hT, x2, idx9);
    k_ac    <<<dim3(49, 4, BB), 256, 0, stream>>>(h, gconv_w, gconv_b, acT);
    k_gather<<<dim3(196, BB), 256, 0, stream>>>(acT, idx9, gT);
    k_fc2   <<<dim3(49, BB), 256, 0, stream>>>(gT, fc2_w, fc2_b, out, sa_in);
    k_att   <<<dim3(13, BB), 256, 0, stream>>>(sa_in, sa_w, x, out);
}

// Round 8
// 319.794 us; speedup vs baseline: 1.2219x; 1.2219x over previous
//
#include <hip/hip_runtime.h>

#define BB 4
#define CC 96
#define NN 3136
#define FLTMAX 3.402823466e+38f

typedef unsigned short ushort_t;
typedef __attribute__((ext_vector_type(8))) short bf16x8;
typedef __attribute__((ext_vector_type(4))) float f32x4;

// fp32 -> bf16 round-to-nearest-even
__device__ __forceinline__ ushort_t f2bf(float f) {
    unsigned u = __float_as_uint(f);
    unsigned r = (u + 0x7fff + ((u >> 16) & 1)) >> 16;
    return (ushort_t)r;
}
__device__ __forceinline__ float bf2f(ushort_t us) {
    return __uint_as_float(((unsigned)us) << 16);
}

// htile layout (per batch):
//   idx(n,c) = (((n>>5)*12 + (c>>3))*32 + (n&31))*8 + (c&7)

// ---------------- K1: fc1 -> h (b,c,n) + x2 + bf16-split htile + hT ----------
__global__ __launch_bounds__(256) void k_fc1(const float* __restrict__ x, const float* __restrict__ w,
                                             const float* __restrict__ bias, float* __restrict__ h,
                                             float* __restrict__ x2g,
                                             ushort_t* __restrict__ hAhi, ushort_t* __restrict__ hAlo,
                                             float* __restrict__ hT) {
    __shared__ float sm[96 * 98 + 96 * 64];
    float* wT = sm;              // [c][o] pad 98
    float* xl = sm + 96 * 98;    // [c][64]
    const int tid = threadIdx.x;
    const int n0 = blockIdx.x * 64;
    const int b = blockIdx.y;
    for (int i = tid; i < 96 * 96; i += 256) {
        int o = i / 96, c = i - o * 96;
        wT[c * 98 + o] = w[i];
    }
    const float* xb = x + (size_t)b * CC * NN;
    for (int i = tid; i < 96 * 64; i += 256) {
        int c = i >> 6, nl = i & 63;
        xl[i] = xb[(size_t)c * NN + n0 + nl];
    }
    __syncthreads();
    const int tr = tid >> 4, tc = tid & 15;
    float acc[6][4];
#pragma unroll
    for (int i = 0; i < 6; ++i)
#pragma unroll
        for (int j = 0; j < 4; ++j) acc[i][j] = 0.f;
#pragma unroll 4
    for (int c = 0; c < 96; ++c) {
        float4 xv = *(const float4*)&xl[c * 64 + tc * 4];
        const float* wp = &wT[c * 98 + tr * 6];
        float2 w01 = *(const float2*)(wp);
        float2 w23 = *(const float2*)(wp + 2);
        float2 w45 = *(const float2*)(wp + 4);
        float wv[6] = {w01.x, w01.y, w23.x, w23.y, w45.x, w45.y};
        float xj[4] = {xv.x, xv.y, xv.z, xv.w};
#pragma unroll
        for (int i = 0; i < 6; ++i)
#pragma unroll
            for (int j = 0; j < 4; ++j) acc[i][j] = fmaf(wv[i], xj[j], acc[i][j]);
    }
    float* hb = h + (size_t)b * CC * NN;
    float* hTb = hT + (size_t)b * NN * 96;
    ushort_t* thi = hAhi + (size_t)b * 602112;
    ushort_t* tlo = hAlo + (size_t)b * 602112;
#pragma unroll
    for (int i = 0; i < 6; ++i) {
        float bi = bias[tr * 6 + i];
        acc[i][0] += bi; acc[i][1] += bi; acc[i][2] += bi; acc[i][3] += bi;
        float4 o4 = make_float4(acc[i][0], acc[i][1], acc[i][2], acc[i][3]);
        *(float4*)&hb[(size_t)(tr * 6 + i) * NN + n0 + tc * 4] = o4;
        const int c = tr * 6 + i;
        const int cpart = c >> 3;   // 12 parts of 8 channels
#pragma unroll
        for (int j = 0; j < 4; ++j) {
            const int n = n0 + tc * 4 + j;
            const int idx = (((n >> 5) * 12 + cpart) * 32 + (n & 31)) * 8 + (c & 7);
            ushort_t hi = f2bf(acc[i][j]);
            float lo = acc[i][j] - bf2f(hi);
            thi[idx] = hi;
            tlo[idx] = f2bf(lo);
            hTb[(size_t)n * 96 + c] = acc[i][j];
        }
    }
    __syncthreads();   // wT/xl reads done -> reuse sm[0..1024) for x2 partials
#pragma unroll
    for (int j = 0; j < 4; ++j) {
        float s = 0.f;
#pragma unroll
        for (int i = 0; i < 6; ++i) s = fmaf(acc[i][j], acc[i][j], s);
        sm[tr * 64 + tc * 4 + j] = s;
    }
    __syncthreads();
    if (tid < 64) {
        float s = 0.f;
#pragma unroll
        for (int t = 0; t < 16; ++t) s += sm[t * 64 + tid];
        x2g[(size_t)b * NN + n0 + tid] = s;
    }
}

// ---------------- K3: MFMA distance + per-lane top-9, 4-way m-split ----------
// grid (49 n-tiles, 4 splits, B), 256 thr = 4 waves.
// Waves (w>>1) own n-halfblock; lane (ln,lq) scans m-stream t=s,s+4,.. (196 vals).
// Per-lane exact top-9 in sorted registers (mask+ctz drain), then per-split LDS
// merge of 4 lq lists -> 9 candidates; 4 splits x 9 = 36 candidates per row.
__global__ __launch_bounds__(256) void k_dist(const ushort_t* __restrict__ hAhi,
                                              const ushort_t* __restrict__ hAlo,
                                              const float* __restrict__ x2,
                                              int* __restrict__ cand_idx) {
    __shared__ float mv[2304];
    __shared__ int   mi[2304];
    const int tid = threadIdx.x;
    const int nt = blockIdx.x, s = blockIdx.y, b = blockIdx.z;
    const int w = tid >> 6, l = tid & 63;
    const int ln = l & 15, lq = l >> 4;
    const int kl_off = lq * 256;
    const ushort_t* hHi = hAhi + (size_t)b * 602112;
    const ushort_t* hLo = hAlo + (size_t)b * 602112;
    const float* x2b = x2 + (size_t)b * NN;

    // preload B-frags (n-side) for 3 k-steps, hi & lo
    const int nblk = nt * 2 + (w >> 1);
    const int lane32n = (w & 1) * 16 + ln;
    bf16x8 bhi[3], blo[3];
#pragma unroll
    for (int ks = 0; ks < 3; ++ks) {
        const int off = nblk * 3072 + ks * 1024 + kl_off + lane32n * 8;
        bhi[ks] = *(const bf16x8*)(hHi + off);
        blo[ks] = *(const bf16x8*)(hLo + off);
    }
    const int aoff0 = kl_off + ln * 8;          // msub even (lane32 = ln)
    const int aoff1 = kl_off + (16 + ln) * 8;   // msub odd  (lane32 = 16+ln)

    // sorted-descending top-9 (lv[0] = worst kept = 9th best)
    float lv[9]; int li[9];
#pragma unroll
    for (int k = 0; k < 9; ++k) { lv[k] = FLTMAX; li[k] = 0x7fffffff; }

    for (int t = s; t < 49; t += 4) {
        const int m0 = t * 64;
        f32x4 acc0 = {0.f, 0.f, 0.f, 0.f};
        f32x4 acc1 = {0.f, 0.f, 0.f, 0.f};
        f32x4 acc2 = {0.f, 0.f, 0.f, 0.f};
        f32x4 acc3 = {0.f, 0.f, 0.f, 0.f};
        const int abase = t * 6144;
#pragma unroll
        for (int ks = 0; ks < 3; ++ks) {
            const int base = abase + ks * 1024;
            // A-hi fragments used twice (x bhi and x blo)
            bf16x8 a0 = *(const bf16x8*)(hHi + base + aoff0);
            bf16x8 a1 = *(const bf16x8*)(hHi + base + aoff1);
            bf16x8 a2 = *(const bf16x8*)(hHi + base + 3072 + aoff0);
            bf16x8 a3 = *(const bf16x8*)(hHi + base + 3072 + aoff1);
            acc0 = __builtin_amdgcn_mfma_f32_16x16x32_bf16(a0, bhi[ks], acc0, 0, 0, 0);
            acc1 = __builtin_amdgcn_mfma_f32_16x16x32_bf16(a1, bhi[ks], acc1, 0, 0, 0);
            acc2 = __builtin_amdgcn_mfma_f32_16x16x32_bf16(a2, bhi[ks], acc2, 0, 0, 0);
            acc3 = __builtin_amdgcn_mfma_f32_16x16x32_bf16(a3, bhi[ks], acc3, 0, 0, 0);
            acc0 = __builtin_amdgcn_mfma_f32_16x16x32_bf16(a0, blo[ks], acc0, 0, 0, 0);
            acc1 = __builtin_amdgcn_mfma_f32_16x16x32_bf16(a1, blo[ks], acc1, 0, 0, 0);
            acc2 = __builtin_amdgcn_mfma_f32_16x16x32_bf16(a2, blo[ks], acc2, 0, 0, 0);
            acc3 = __builtin_amdgcn_mfma_f32_16x16x32_bf16(a3, blo[ks], acc3, 0, 0, 0);
            bf16x8 c0 = *(const bf16x8*)(hLo + base + aoff0);
            bf16x8 c1 = *(const bf16x8*)(hLo + base + aoff1);
            bf16x8 c2 = *(const bf16x8*)(hLo + base + 3072 + aoff0);
            bf16x8 c3 = *(const bf16x8*)(hLo + base + 3072 + aoff1);
            acc0 = __builtin_amdgcn_mfma_f32_16x16x32_bf16(c0, bhi[ks], acc0, 0, 0, 0);
            acc1 = __builtin_amdgcn_mfma_f32_16x16x32_bf16(c1, bhi[ks], acc1, 0, 0, 0);
            acc2 = __builtin_amdgcn_mfma_f32_16x16x32_bf16(c2, bhi[ks], acc2, 0, 0, 0);
            acc3 = __builtin_amdgcn_mfma_f32_16x16x32_bf16(c3, bhi[ks], acc3, 0, 0, 0);
        }
        // scan: lane owns n; rows m = m0 + msub*16 + lq*4 + r
#pragma unroll
        for (int msub = 0; msub < 4; ++msub) {
            f32x4 a = (msub == 0) ? acc0 : (msub == 1) ? acc1 : (msub == 2) ? acc2 : acc3;
            const int mb = m0 + msub * 16 + lq * 4;
            float4 xv = *(const float4*)&x2b[mb];
            float s0 = fmaf(-2.f, a[0], xv.x);
            float s1 = fmaf(-2.f, a[1], xv.y);
            float s2 = fmaf(-2.f, a[2], xv.z);
            float s3 = fmaf(-2.f, a[3], xv.w);
            unsigned msk = (s0 < lv[0] ? 1u : 0u) | (s1 < lv[0] ? 2u : 0u) |
                           (s2 < lv[0] ? 4u : 0u) | (s3 < lv[0] ? 8u : 0u);
            while (msk) {
                const int r = __builtin_ctz(msk);
                msk &= msk - 1;
                float v01 = (r & 1) ? s1 : s0;
                float v23 = (r & 1) ? s3 : s2;
                float v = (r & 2) ? v23 : v01;
                const int m = mb + r;
                // guarded branchless sorted insert (drop old head = old 9th-best)
                const bool p_ = v < lv[0];
                float cv = p_ ? v : lv[0];
                int ci = p_ ? m : li[0];
#pragma unroll
                for (int k = 1; k < 9; ++k) {
                    float ok = lv[k]; int oi = li[k];
                    const bool sw = ok > cv;
                    lv[k - 1] = sw ? ok : cv;
                    li[k - 1] = sw ? oi : ci;
                    cv = sw ? cv : ok;
                    ci = sw ? ci : oi;
                }
                lv[8] = cv; li[8] = ci;
            }
        }
    }

    // per-split merge: 4 lq lists per n -> split top-9
    const int nloc = (w >> 1) * 32 + lane32n;   // 0..63
    const int slot = (nloc * 4 + lq) * 9;
#pragma unroll
    for (int k = 0; k < 9; ++k) { mv[slot + k] = lv[k]; mi[slot + k] = li[k]; }
    __syncthreads();
    if (tid < 64) {
        const int base = tid * 36;
        int* dst = cand_idx + ((size_t)b * NN + nt * 64 + tid) * 36 + s * 9;
        for (int kk = 0; kk < 9; ++kk) {
            float bv = FLTMAX; int bi = 0x7fffffff; int bs = 0;
            for (int j = 0; j < 36; ++j) {
                float v = mv[base + j]; int ii = mi[base + j];
                if (v < bv || (v == bv && ii < bi)) { bv = v; bi = ii; bs = j; }
            }
            mv[base + bs] = FLTMAX;
            dst[kk] = bi;
        }
    }
}

// ---------------- K4: exact fp32 rescore of 36 candidates -> idx9 ------------
// grid 196 blocks x 256 thr: 4 threads per row n, 64 rows per block.
__global__ __launch_bounds__(256) void k_merge(const int* __restrict__ cand_idx,
                                               const float* __restrict__ hT,
                                               const float* __restrict__ x2,
                                               int* __restrict__ idx9) {
    __shared__ float mv[64 * 36];
    __shared__ int   mi[64 * 36];
    const int tid = threadIdx.x;
    const int nl = tid >> 2, part = tid & 3;
    const int n = blockIdx.x * 64 + nl;     // global row id in [0, BB*NN)
    const int b = n / NN;
    const int nn = n - b * NN;
    const float* hTb = hT + (size_t)b * NN * 96;
    const float* x2b = x2 + (size_t)b * NN;
    float4 ro[24];
    {
        const float* own = hTb + (size_t)nn * 96;
#pragma unroll
        for (int i = 0; i < 24; ++i) ro[i] = *(const float4*)&own[i * 4];
    }
#pragma unroll
    for (int jj = 0; jj < 9; ++jj) {
        const int j = part * 9 + jj;
        const int cj = cand_idx[(size_t)n * 36 + j];
        const float* cr = hTb + (size_t)cj * 96;
        float dot = 0.f;
#pragma unroll
        for (int i = 0; i < 24; ++i) {
            float4 cv = *(const float4*)&cr[i * 4];
            dot = fmaf(ro[i].x, cv.x, dot);
            dot = fmaf(ro[i].y, cv.y, dot);
            dot = fmaf(ro[i].z, cv.z, dot);
            dot = fmaf(ro[i].w, cv.w, dot);
        }
        mv[nl * 36 + j] = fmaf(-2.f, dot, x2b[cj]);
        mi[nl * 36 + j] = cj;
    }
    __syncthreads();
    if (tid < 64) {
        const int base = tid * 36;
        const size_t grow = (size_t)(blockIdx.x * 64 + tid);
        for (int kk = 0; kk < 9; ++kk) {
            float bv = FLTMAX; int bi = 0x7fffffff; int bs = 0;
            for (int j = 0; j < 36; ++j) {
                float v = mv[base + j]; int ii = mi[base + j];
                if (v < bv || (v == bv && ii < bi)) { bv = v; bi = ii; bs = j; }
            }
            mv[base + bs] = FLTMAX;
            idx9[grow * 9 + kk] = bi;
        }
    }
}

// ---------------- K5: [U;V] @ h -> acT (b,n,384); weight transform fused -----
__global__ __launch_bounds__(256) void k_ac(const float* __restrict__ h, const float* __restrict__ gw,
                                            const float* __restrict__ gb, float* __restrict__ acT) {
    __shared__ float sm[96 * 98 + 96 * 64];
    float* wT = sm;
    float* hl = sm + 96 * 98;
    const int tid = threadIdx.x;
    const int n0 = blockIdx.x * 64, ot = blockIdx.y, b = blockIdx.z;
    // rows 0..191 of M = W1 - W2, rows 192..383 = W2  (W=[W1|W2], 192x192)
    for (int i = tid; i < 96 * 96; i += 256) {
        int o = i / 96, c = i - o * 96;
        float v;
        if (ot < 2) {
            const float* gwp = gw + (size_t)(ot * 96 + o) * 192;
            v = gwp[c] - gwp[96 + c];
        } else {
            v = gw[(size_t)((ot - 2) * 96 + o) * 192 + 96 + c];
        }
        wT[c * 98 + o] = v;
    }
    const float* hb = h + (size_t)b * CC * NN;
    for (int i = tid; i < 96 * 64; i += 256) {
        int c = i >> 6, nl = i & 63;
        hl[i] = hb[(size_t)c * NN + n0 + nl];
    }
    __syncthreads();
    const int tr = tid >> 4, tc = tid & 15;
    float acc[6][4];
#pragma unroll
    for (int i = 0; i < 6; ++i)
#pragma unroll
        for (int j = 0; j < 4; ++j) acc[i][j] = 0.f;
#pragma unroll 4
    for (int c = 0; c < 96; ++c) {
        float4 xv = *(const float4*)&hl[c * 64 + tc * 4];
        const float* wp = &wT[c * 98 + tr * 6];
        float2 w01 = *(const float2*)(wp);
        float2 w23 = *(const float2*)(wp + 2);
        float2 w45 = *(const float2*)(wp + 4);
        float wv[6] = {w01.x, w01.y, w23.x, w23.y, w45.x, w45.y};
        float xj[4] = {xv.x, xv.y, xv.z, xv.w};
#pragma unroll
        for (int i = 0; i < 6; ++i)
#pragma unroll
            for (int j = 0; j < 4; ++j) acc[i][j] = fmaf(wv[i], xj[j], acc[i][j]);
    }
    const int obase = ot * 96 + tr * 6;
    float bs[6];
#pragma unroll
    for (int i = 0; i < 6; ++i) bs[i] = (ot < 2) ? gb[obase + i] : 0.f;
#pragma unroll
    for (int j = 0; j < 4; ++j) {
        float* dst = acT + ((size_t)b * NN + n0 + tc * 4 + j) * 384 + obase;
        *(float2*)(dst + 0) = make_float2(acc[0][j] + bs[0], acc[1][j] + bs[1]);
        *(float2*)(dst + 2) = make_float2(acc[2][j] + bs[2], acc[3][j] + bs[3]);
        *(float2*)(dst + 4) = make_float2(acc[4][j] + bs[4], acc[5][j] + bs[5]);
    }
}

// ---------------- K6: gather neighbors, k-max, relu -> gT (b,n,192) ----------
__global__ __launch_bounds__(256) void k_gather(const float* __restrict__ acT, const int* __restrict__ idx9,
                                                float* __restrict__ gT) {
    const int lane = threadIdx.x & 63;
    const int wv = threadIdx.x >> 6;
    const int b = blockIdx.y;
    const int nb = blockIdx.x * 16 + wv * 4;
    for (int r = 0; r < 4; ++r) {
        const int n = nb + r;
        const float* ar = acT + ((size_t)b * NN + n) * 384;
        float a0 = ar[lane], a1 = ar[lane + 64], a2 = ar[lane + 128];
        const int* ip = idx9 + ((size_t)b * NN + n) * 9;
        int jj[9];
#pragma unroll
        for (int k = 0; k < 9; ++k) jj[k] = ip[k];
        float m0 = -FLTMAX, m1 = -FLTMAX, m2 = -FLTMAX;
#pragma unroll
        for (int k = 0; k < 9; ++k) {
            const float* cr = acT + ((size_t)b * NN + jj[k]) * 384 + 192;
            m0 = fmaxf(m0, a0 + cr[lane]);
            m1 = fmaxf(m1, a1 + cr[lane + 64]);
            m2 = fmaxf(m2, a2 + cr[lane + 128]);
        }
        float* gr = gT + ((size_t)b * NN + n) * 192;
        gr[lane] = fmaxf(m0, 0.f);
        gr[lane + 64] = fmaxf(m1, 0.f);
        gr[lane + 128] = fmaxf(m2, 0.f);
    }
}

// ---------------- K7: fc2 (NT gemm) -> out, fused channel mean/max -----------
__global__ __launch_bounds__(256) void k_fc2(const float* __restrict__ gT, const float* __restrict__ w,
                                             const float* __restrict__ bias, float* __restrict__ out,
                                             float* __restrict__ sa_in) {
    __shared__ float Wc[96 * 36];
    __shared__ float Gc[64 * 36];
    const int tid = threadIdx.x;
    const int n0 = blockIdx.x * 64, b = blockIdx.y;
    const int tr = tid >> 4, tc = tid & 15;
    float acc[6][4];
#pragma unroll
    for (int i = 0; i < 6; ++i)
#pragma unroll
        for (int j = 0; j < 4; ++j) acc[i][j] = 0.f;
    for (int kc = 0; kc < 192; kc += 32) {
        for (int i = tid; i < 96 * 32; i += 256) {
            int c = i >> 5, k = i & 31;
            Wc[c * 36 + k] = w[(size_t)c * 192 + kc + k];
        }
        for (int i = tid; i < 64 * 32; i += 256) {
            int nl = i >> 5, k = i & 31;
            Gc[nl * 36 + k] = gT[((size_t)b * NN + n0 + nl) * 192 + kc + k];
        }
        __syncthreads();
#pragma unroll
        for (int k = 0; k < 32; k += 4) {
            float4 wv[6]; float4 gv[4];
#pragma unroll
            for (int i = 0; i < 6; ++i) wv[i] = *(const float4*)&Wc[(tr * 6 + i) * 36 + k];
#pragma unroll
            for (int j = 0; j < 4; ++j) gv[j] = *(const float4*)&Gc[(tc * 4 + j) * 36 + k];
#pragma unroll
            for (int i = 0; i < 6; ++i)
#pragma unroll
                for (int j = 0; j < 4; ++j) {
                    acc[i][j] = fmaf(wv[i].x, gv[j].x, acc[i][j]);
                    acc[i][j] = fmaf(wv[i].y, gv[j].y, acc[i][j]);
                    acc[i][j] = fmaf(wv[i].z, gv[j].z, acc[i][j]);
                    acc[i][j] = fmaf(wv[i].w, gv[j].w, acc[i][j]);
                }
        }
        __syncthreads();
    }
    float* ob = out + (size_t)b * CC * NN;
    float bs[6];
#pragma unroll
    for (int i = 0; i < 6; ++i) bs[i] = bias[tr * 6 + i];
    float ps[4], pm[4];
#pragma unroll
    for (int j = 0; j < 4; ++j) { ps[j] = 0.f; pm[j] = -FLTMAX; }
#pragma unroll
    for (int i = 0; i < 6; ++i) {
        float o0 = acc[i][0] + bs[i], o1 = acc[i][1] + bs[i];
        float o2 = acc[i][2] + bs[i], o3 = acc[i][3] + bs[i];
        *(float4*)&ob[(size_t)(tr * 6 + i) * NN + n0 + tc * 4] = make_float4(o0, o1, o2, o3);
        ps[0] += o0; ps[1] += o1; ps[2] += o2; ps[3] += o3;
        pm[0] = fmaxf(pm[0], o0); pm[1] = fmaxf(pm[1], o1);
        pm[2] = fmaxf(pm[2], o2); pm[3] = fmaxf(pm[3], o3);
    }
    // channel mean/max reduction across tr (16 groups of 6 channels)
    float* red  = Wc;          // [16][64]
    float* red2 = Wc + 1024;   // [16][64]
#pragma unroll
    for (int j = 0; j < 4; ++j) {
        red[tr * 64 + tc * 4 + j]  = ps[j];
        red2[tr * 64 + tc * 4 + j] = pm[j];
    }
    __syncthreads();
    if (tid < 64) {
        float s_ = 0.f, m_ = -FLTMAX;
#pragma unroll
        for (int t = 0; t < 16; ++t) { s_ += red[t * 64 + tid]; m_ = fmaxf(m_, red2[t * 64 + tid]); }
        sa_in[(size_t)b * 2 * NN + n0 + tid] = s_ * (1.0f / 96.0f);
        sa_in[(size_t)b * 2 * NN + NN + n0 + tid] = m_;
    }
}

// ---------------- K9: 7x7 conv + sigmoid + out*att + shortcut (in place) -----
__global__ __launch_bounds__(256) void k_att(const float* __restrict__ sa_in, const float* __restrict__ sw,
                                             const float* __restrict__ x, float* __restrict__ out) {
    int n = blockIdx.x * 256 + threadIdx.x;
    int b = blockIdx.y;
    if (n >= NN) return;
    int y = n / 56, xw = n - y * 56;
    float acc = 0.f;
#pragma unroll
    for (int ci = 0; ci < 2; ++ci) {
        const float* sb = sa_in + ((size_t)b * 2 + ci) * NN;
#pragma unroll
        for (int dy = 0; dy < 7; ++dy) {
            int yy = y + dy - 3;
            if ((unsigned)yy < 56u) {
#pragma unroll
                for (int dx = 0; dx < 7; ++dx) {
                    int xx = xw + dx - 3;
                    if ((unsigned)xx < 56u)
                        acc = fmaf(sb[yy * 56 + xx], sw[(ci * 7 + dy) * 7 + dx], acc);
                }
            }
        }
    }
    float att = 1.f / (1.f + expf(-acc));
    const float* xb = x + (size_t)b * CC * NN + n;
    float* ob = out + (size_t)b * CC * NN + n;
#pragma unroll 4
    for (int c = 0; c < 96; ++c) {
        size_t o = (size_t)c * NN;
        ob[o] = fmaf(ob[o], att, xb[o]);
    }
}

extern "C" void kernel_launch(void* const* d_in, const int* in_sizes, int n_in,
                              void* d_out, int out_size, void* d_ws, size_t ws_size,
                              hipStream_t stream) {
    (void)in_sizes; (void)n_in; (void)out_size; (void)ws_size;
    const float* x       = (const float*)d_in[0];
    const float* fc1_w   = (const float*)d_in[1];
    const float* fc1_b   = (const float*)d_in[2];
    const float* gconv_w = (const float*)d_in[3];
    const float* gconv_b = (const float*)d_in[4];
    const float* fc2_w   = (const float*)d_in[5];
    const float* fc2_b   = (const float*)d_in[6];
    const float* sa_w    = (const float*)d_in[7];
    float* out = (float*)d_out;

    // workspace layout (floats)
    float* ws   = (float*)d_ws;
    float* h    = ws;                                   // 1,204,224
    float* x2   = h + (size_t)BB * CC * NN;             // 12,544
    int*   idx9 = (int*)(x2 + BB * NN);                 // 112,896 ints
    float* acT  = (float*)(idx9 + (size_t)BB * NN * 9); // 4,816,896
    float* gT   = acT + (size_t)BB * NN * 384;          // 2,408,448
    // overlays (disjoint lifetimes):
    // acT region: [hAhi | hAlo | hT] live k_fc1 -> k_merge; acT written by k_ac after
    ushort_t* hAhi = (ushort_t*)acT;                    // per batch 602112 ushorts
    ushort_t* hAlo = hAhi + (size_t)BB * 602112;
    float* hT = acT + (size_t)2408448;                  // 1,204,224 floats
    // cand_idx lives in gT region (written k_dist, read k_merge; gT written k_gather later)
    int* cand_idx = (int*)gT;                           // 12544*36 ints
    float* sa_in = gT + (size_t)BB * NN * 192;          // 25,088

    k_fc1   <<<dim3(49, BB), 256, 0, stream>>>(x, fc1_w, fc1_b, h, x2, hAhi, hAlo, hT);
    k_dist  <<<dim3(49, 4, BB), 256, 0, stream>>>(hAhi, hAlo, x2, cand_idx);
    k_merge <<<dim3(196), 256, 0, stream>>>(cand_idx, hT, x2, idx9);
    k_ac    <<<dim3(49, 4, BB), 256, 0, stream>>>(h, gconv_w, gconv_b, acT);
    k_gather<<<dim3(196, BB), 256, 0, stream>>>(acT, idx9, gT);
    k_fc2   <<<dim3(49, BB), 256, 0, stream>>>(gT, fc2_w, fc2_b, out, sa_in);
    k_att   <<<dim3(13, BB), 256, 0, stream>>>(sa_in, sa_w, x, out);
}